// Round 7
// baseline (88.988 us; speedup 1.0000x reference)
//
#include <hip/hip_runtime.h>
#include <math.h>

#define EPSF    1e-8f
#define W_MINF  0.005f
#define BETAF   0.02f
#define LOG2E   1.4426950408889634f

constexpr double KD    = 1.4426950408889634 / 0.02;   // log2(e)/beta
constexpr float  K2F   = (float)(KD * KD);            // folded into A,B,C
constexpr float  K2EPS = (float)(KD * KD * 1e-8);     // scaled eps
constexpr float  INVK  = (float)(1.0 / KD);

typedef float v2f __attribute__((ext_vector_type(2)));

__device__ __forceinline__ float fast_exp(float x) {   // e^x
    return __builtin_amdgcn_exp2f(x * LOG2E);
}
__device__ __forceinline__ float sigm(float x) {       // 1/(1+e^-x)
    return 1.0f / (1.0f + fast_exp(-x));
}
__device__ __forceinline__ float ex2(float x) { return __builtin_amdgcn_exp2f(x); }

__device__ __forceinline__ unsigned min3u(unsigned a, unsigned b, unsigned c) {
    unsigned d;
    asm("v_min3_u32 %0, %1, %2, %3" : "=v"(d) : "v"(a), "v"(b), "v"(c));
    return d;
}
__device__ __forceinline__ unsigned med3u(unsigned a, unsigned b, unsigned c) {
    unsigned d;
    asm("v_med3_u32 %0, %1, %2, %3" : "=v"(d) : "v"(a), "v"(b), "v"(c));
    return d;
}

// ---- kernel A: per-seed table (SoA: A,B,C,sx,sy) into d_ws ---------------
// r = A*dx^2 + 2C*dx*dy + B*dy^2 + K2EPS  (= (K*d)^2) from dx,dy (accurate)
extern "C" __global__ __launch_bounds__(512)
void seed_prep(const float* __restrict__ seeds,
               const float* __restrict__ theta,
               const float* __restrict__ a_raw,
               float* __restrict__ ws, int S)
{
    int j = blockIdx.x * blockDim.x + threadIdx.x;
    if (j >= S) return;
    float sx = seeds[2 * j + 0];
    float sy = seeds[2 * j + 1];
    float sn, cs;
    __sincosf(theta[j], &sn, &cs);
    float a   = 0.5f + 1.5f * sigm(a_raw[j]);
    float a2  = a * a;
    float ia2 = 1.0f / a2;
    float c2 = cs * cs, s2 = sn * sn;
    ws[0 * 512 + j] = K2F * (c2 * a2 + s2 * ia2);          // A
    ws[1 * 512 + j] = K2F * (s2 * a2 + c2 * ia2);          // B
    ws[2 * 512 + j] = K2F * (cs * sn * (a2 - ia2));        // C
    ws[3 * 512 + j] = sx;
    ws[4 * 512 + j] = sy;
}

// ---- kernel B: 64 queries/block (lanes), 8 waves = 8 seed partitions -----
// Seed tables staged in LDS; inner-loop reads are wave-uniform ds_read_b64
// broadcasts (conflict-free), no VMEM/SMEM in the loop.
extern "C" __global__ __launch_bounds__(512, 8)
void voronoi_kernel(const float* __restrict__ uv,
                    const float* __restrict__ w_raw,
                    const float* __restrict__ h_raw,
                    const float* __restrict__ gap_thr_raw,
                    const float* __restrict__ big_thr_raw,
                    const float* __restrict__ alpha_raw,
                    const float* __restrict__ eta_raw,
                    const float* __restrict__ ws,
                    float* __restrict__ out,
                    int Q, int S)
{
    __shared__ float sA[512], sB[512], sC[512], sX[512], sY[512];   // 10 KB
    __shared__ unsigned mv1[8][64], mv2[8][64];                     //  4 KB
    __shared__ float    ms1[8][64], ms2[8][64];                     //  4 KB

    const int tid = threadIdx.x;
    {   // coalesced one-shot staging (blockDim == 512 == S)
        sA[tid] = ws[0 * 512 + tid];
        sB[tid] = ws[1 * 512 + tid];
        sC[tid] = ws[2 * 512 + tid];
        sX[tid] = ws[3 * 512 + tid];
        sY[tid] = ws[4 * 512 + tid];
    }
    __syncthreads();

    const int part = __builtin_amdgcn_readfirstlane((int)(tid >> 6));
    const int lane = tid & 63;
    const int q    = blockIdx.x * 64 + lane;
    const int qc   = q < Q ? q : (Q - 1);

    const float2 u = *reinterpret_cast<const float2*>(&uv[2 * qc]);
    const v2f uxv  = { u.x, u.x };
    const v2f uyv  = { u.y, u.y };
    const v2f epsv = { K2EPS, K2EPS };

    unsigned v1u = 0x7F7FFFFFu, v2u = 0x7F7FFFFFu;  // packed (r-bits|index)
    v2f s1v = { 0.0f, 0.0f };
    v2f s2v = { 0.0f, 0.0f };

    const int base = part * 64;
    #pragma unroll 4
    for (int t = 0; t < 64; t += 2) {
        const int j = base + t;                   // wave-uniform LDS broadcast
        const v2f A  = *reinterpret_cast<const v2f*>(&sA[j]);
        const v2f B  = *reinterpret_cast<const v2f*>(&sB[j]);
        const v2f C  = *reinterpret_cast<const v2f*>(&sC[j]);
        const v2f sx = *reinterpret_cast<const v2f*>(&sX[j]);
        const v2f sy = *reinterpret_cast<const v2f*>(&sY[j]);

        v2f dx = uxv - sx;
        v2f dy = uyv - sy;
        v2f p  = A * dx + C * dy;
        v2f qv = C * dx + B * dy;
        v2f r  = dx * p + (dy * qv + epsv);       // (K*d)^2, accurate

        float e0 = ex2(-__builtin_amdgcn_sqrtf(r.x));  // exp(-d/beta)
        float e1 = ex2(-__builtin_amdgcn_sqrtf(r.y));
        v2f e = { e0, e1 };
        s1v = s1v + e;
        s2v = e * e + s2v;

        // pack index into low 9 mantissa bits: one v_and_or_b32 per seed
        unsigned pv0 = (__float_as_uint(r.x) & 0xFFFFFE00u) | (unsigned)j;
        unsigned pv1 = (__float_as_uint(r.y) & 0xFFFFFE00u) | (unsigned)(j + 1);
        unsigned m2  = med3u(v1u, pv0, pv1);      // 2nd-smallest of {v1,p0,p1}
        v1u = min3u(v1u, pv0, pv1);
        v2u = v2u < m2 ? v2u : m2;
    }

    float s1 = s1v.x + s1v.y;
    float s2 = s2v.x + s2v.y;

    // ---- merge 8 per-wave partials through LDS ---------------------------
    mv1[part][lane] = v1u;  mv2[part][lane] = v2u;
    ms1[part][lane] = s1;   ms2[part][lane] = s2;
    __syncthreads();
    if (part != 0) return;

    unsigned V1 = mv1[0][lane], V2 = mv2[0][lane];
    float    S1 = ms1[0][lane], S2 = ms2[0][lane];
    #pragma unroll
    for (int p2 = 1; p2 < 8; ++p2) {
        unsigned w1 = mv1[p2][lane], w2 = mv2[p2][lane];
        S1 += ms1[p2][lane];
        S2 += ms2[p2][lane];
        unsigned n1 = V1 < w1 ? V1 : w1;
        unsigned hi = V1 > w1 ? V1 : w1;
        unsigned l2 = V2 < w2 ? V2 : w2;
        V2 = hi < l2 ? hi : l2;
        V1 = n1;
    }

    const int i1 = (int)(V1 & 511u);
    const int i2 = (int)(V2 & 511u);
    float d1K = __builtin_amdgcn_sqrtf(__uint_as_float(V1));   // K*d1
    float d2K = __builtin_amdgcn_sqrtf(__uint_as_float(V2));
    float d1  = d1K * INVK;
    float gap = (d2K - d1K) * INVK;

    float sp2  = (S2 / S1) / S1;                 // sum p^2 (underflow-safe)
    float keff = 1.0f / (sp2 + EPSF);
    float jfac = sigm((keff - 3.0f) * (1.0f / 0.35f));

    float ddx   = sX[i1] - sX[i2];
    float ddy   = sY[i1] - sY[i2];
    float pdist = __builtin_amdgcn_sqrtf(fmaf(ddx, ddx, fmaf(ddy, ddy, EPSF)));
    float wmax  = fmaxf(0.8f * pdist, W_MINF + EPSF);
    float sij   = sigm(w_raw[i1 * S + i2] * 0.2f);   // /RAW_TEMP(5)
    float sji   = sigm(w_raw[i2 * S + i1] * 0.2f);
    float wpair = W_MINF + (wmax - W_MINF) * 0.5f * (sij + sji);

    float weff     = wpair * fmaf(0.15f, jfac, 1.0f);
    float beta_eff = BETAF * fmaf(0.05f, jfac, 1.0f);
    float wall     = sigm((weff - gap) / beta_eff);

    float gap_thr = 0.5f  * sigm(gap_thr_raw[0]);
    float big_thr = 0.6f  * sigm(big_thr_raw[0]);
    float alpha_g = 0.01f + 0.19f * sigm(alpha_raw[0]);
    float eta_g   = 0.01f + 0.19f * sigm(eta_raw[0]);

    float gate = sigm((gap_thr - gap) / alpha_g) * sigm((big_thr - d1) / eta_g);

    float t      = fmaxf(keff - 3.0f, 0.0f);
    float triple = 0.15f * t * __builtin_amdgcn_sqrtf(t);

    float h   = 0.5f + 1.5f * sigm(h_raw[0]);
    float occ = fminf(fmaxf(fmaf(wall, gate, triple), 0.0f), 1.0f);
    if (q < Q) out[q] = occ * h;
}

extern "C" void kernel_launch(void* const* d_in, const int* in_sizes, int n_in,
                              void* d_out, int out_size, void* d_ws, size_t ws_size,
                              hipStream_t stream)
{
    const float* uv          = (const float*)d_in[0];
    const float* seeds_raw   = (const float*)d_in[1];
    const float* w_raw       = (const float*)d_in[2];
    const float* h_raw       = (const float*)d_in[3];
    const float* theta       = (const float*)d_in[4];
    const float* a_raw       = (const float*)d_in[5];
    const float* gap_thr_raw = (const float*)d_in[6];
    const float* big_thr_raw = (const float*)d_in[7];
    const float* alpha_raw   = (const float*)d_in[8];
    const float* eta_raw     = (const float*)d_in[9];
    float* out = (float*)d_out;
    float* ws  = (float*)d_ws;

    const int Q = in_sizes[0] / 2;
    const int S = in_sizes[4];

    seed_prep<<<dim3((S + 511) / 512), dim3(512), 0, stream>>>(seeds_raw, theta,
                                                               a_raw, ws, S);

    dim3 block(512);                      // 8 waves: 8 seed-partitions
    dim3 grid((Q + 63) / 64);             // 64 queries per block
    voronoi_kernel<<<grid, block, 0, stream>>>(uv, w_raw, h_raw,
                                               gap_thr_raw, big_thr_raw,
                                               alpha_raw, eta_raw,
                                               ws, out, Q, S);
}

// Round 8
// 86.931 us; speedup vs baseline: 1.0237x; 1.0237x over previous
//
#include <hip/hip_runtime.h>
#include <math.h>

#define EPSF    1e-8f
#define W_MINF  0.005f
#define BETAF   0.02f
#define LOG2E   1.4426950408889634f

constexpr double KD    = 1.4426950408889634 / 0.02;   // log2(e)/beta
constexpr float  K2F   = (float)(KD * KD);            // folded into A,B,C
constexpr float  K2EPS = (float)(KD * KD * 1e-8);     // scaled eps
constexpr float  INVK  = (float)(1.0 / KD);

typedef float v2f __attribute__((ext_vector_type(2)));
typedef float v4f __attribute__((ext_vector_type(4)));

__device__ __forceinline__ float fast_exp(float x) {   // e^x
    return __builtin_amdgcn_exp2f(x * LOG2E);
}
__device__ __forceinline__ float sigm(float x) {       // 1/(1+e^-x)
    return 1.0f / (1.0f + fast_exp(-x));
}
__device__ __forceinline__ float ex2(float x) { return __builtin_amdgcn_exp2f(x); }

__device__ __forceinline__ unsigned min3u(unsigned a, unsigned b, unsigned c) {
    unsigned d;
    asm("v_min3_u32 %0, %1, %2, %3" : "=v"(d) : "v"(a), "v"(b), "v"(c));
    return d;
}
__device__ __forceinline__ unsigned med3u(unsigned a, unsigned b, unsigned c) {
    unsigned d;
    asm("v_med3_u32 %0, %1, %2, %3" : "=v"(d) : "v"(a), "v"(b), "v"(c));
    return d;
}

// Fused kernel: 64 queries/block (lanes), 8 waves = 8 seed partitions.
// Seed prep done in-block straight into LDS (no seed_prep launch, no ws).
// AoS pair layout per group g (seeds 2g,2g+1), 12 floats / 48 B stride:
//   [A0,A1,B0,B1,  C0,C1,X0,X1,  Y0,Y1,-,-]  -> b128 + b128 + b64 per iter.
extern "C" __global__ __launch_bounds__(512, 8)
void voronoi_kernel(const float* __restrict__ uv,
                    const float* __restrict__ seeds,
                    const float* __restrict__ theta,
                    const float* __restrict__ a_raw,
                    const float* __restrict__ w_raw,
                    const float* __restrict__ h_raw,
                    const float* __restrict__ gap_thr_raw,
                    const float* __restrict__ big_thr_raw,
                    const float* __restrict__ alpha_raw,
                    const float* __restrict__ eta_raw,
                    float* __restrict__ out,
                    int Q, int S)
{
    __shared__ float sg[256 * 12];                    // 12 KB seed table
    __shared__ unsigned mv1[8][64], mv2[8][64];       //  4 KB
    __shared__ float    ms1[8][64], ms2[8][64];       //  4 KB

    const int tid = threadIdx.x;
    {   // in-block seed prep: thread tid preps seed tid (blockDim == S == 512)
        const int j = tid;
        float sx = seeds[2 * j + 0];
        float sy = seeds[2 * j + 1];
        float sn, cs;
        __sincosf(theta[j], &sn, &cs);
        float a   = 0.5f + 1.5f * sigm(a_raw[j]);
        float a2  = a * a;
        float ia2 = 1.0f / a2;
        float c2 = cs * cs, s2 = sn * sn;
        float* p = &sg[(j >> 1) * 12 + (j & 1)];
        p[0] = K2F * (c2 * a2 + s2 * ia2);            // A
        p[2] = K2F * (s2 * a2 + c2 * ia2);            // B
        p[4] = K2F * (cs * sn * (a2 - ia2));          // C
        p[6] = sx;                                    // X
        p[8] = sy;                                    // Y
    }
    __syncthreads();

    const int part = __builtin_amdgcn_readfirstlane((int)(tid >> 6));
    const int lane = tid & 63;
    const int q    = blockIdx.x * 64 + lane;
    const int qc   = q < Q ? q : (Q - 1);

    const float2 u = *reinterpret_cast<const float2*>(&uv[2 * qc]);
    const v2f uxv  = { u.x, u.x };
    const v2f uyv  = { u.y, u.y };
    const v2f epsv = { K2EPS, K2EPS };

    unsigned v1u = 0x7F7FFFFFu, v2u = 0x7F7FFFFFu;  // packed (r-bits|index)
    v2f s1v = { 0.0f, 0.0f };
    v2f s2v = { 0.0f, 0.0f };

    const int gbase = part * 32;                     // 32 groups = 64 seeds
    #pragma unroll 8
    for (int g = 0; g < 32; ++g) {
        const float* pp = &sg[(gbase + g) * 12];     // wave-uniform broadcast
        const v4f r0 = *reinterpret_cast<const v4f*>(pp + 0);  // A0 A1 B0 B1
        const v4f r1 = *reinterpret_cast<const v4f*>(pp + 4);  // C0 C1 X0 X1
        const v2f r2 = *reinterpret_cast<const v2f*>(pp + 8);  // Y0 Y1
        const v2f A = { r0.x, r0.y };
        const v2f B = { r0.z, r0.w };
        const v2f C = { r1.x, r1.y };
        const v2f X = { r1.z, r1.w };

        v2f dx = uxv - X;                            // pk_add (neg mod)
        v2f dy = uyv - r2;
        v2f p  = __builtin_elementwise_fma(A, dx, C * dy);   // pk_mul+pk_fma
        v2f qv = __builtin_elementwise_fma(C, dx, B * dy);
        v2f r  = __builtin_elementwise_fma(
                     dx, p, __builtin_elementwise_fma(dy, qv, epsv));

        float e0 = ex2(-__builtin_amdgcn_sqrtf(r.x));        // exp(-d/beta)
        float e1 = ex2(-__builtin_amdgcn_sqrtf(r.y));
        v2f e = { e0, e1 };
        s1v = s1v + e;                                        // pk_add
        s2v = __builtin_elementwise_fma(e, e, s2v);           // pk_fma

        const int j0 = (gbase + g) * 2;
        unsigned pv0 = (__float_as_uint(r.x) & 0xFFFFFE00u) | (unsigned)j0;
        unsigned pv1 = (__float_as_uint(r.y) & 0xFFFFFE00u) | (unsigned)(j0 + 1);
        unsigned m2  = med3u(v1u, pv0, pv1);         // 2nd-smallest of {v1,p0,p1}
        v1u = min3u(v1u, pv0, pv1);
        v2u = v2u < m2 ? v2u : m2;
    }

    float s1 = s1v.x + s1v.y;
    float s2 = s2v.x + s2v.y;

    // ---- merge 8 per-wave partials through LDS ---------------------------
    mv1[part][lane] = v1u;  mv2[part][lane] = v2u;
    ms1[part][lane] = s1;   ms2[part][lane] = s2;
    __syncthreads();
    if (part != 0) return;

    unsigned V1 = mv1[0][lane], V2 = mv2[0][lane];
    float    S1 = ms1[0][lane], S2 = ms2[0][lane];
    #pragma unroll
    for (int p2 = 1; p2 < 8; ++p2) {
        unsigned w1 = mv1[p2][lane], w2 = mv2[p2][lane];
        S1 += ms1[p2][lane];
        S2 += ms2[p2][lane];
        unsigned n1 = V1 < w1 ? V1 : w1;
        unsigned hi = V1 > w1 ? V1 : w1;
        unsigned l2 = V2 < w2 ? V2 : w2;
        V2 = hi < l2 ? hi : l2;
        V1 = n1;
    }

    const int i1 = (int)(V1 & 511u);
    const int i2 = (int)(V2 & 511u);
    float d1K = __builtin_amdgcn_sqrtf(__uint_as_float(V1));   // K*d1
    float d2K = __builtin_amdgcn_sqrtf(__uint_as_float(V2));
    float d1  = d1K * INVK;
    float gap = (d2K - d1K) * INVK;

    float sp2  = (S2 / S1) / S1;                 // sum p^2 (underflow-safe)
    float keff = 1.0f / (sp2 + EPSF);
    float jfac = sigm((keff - 3.0f) * (1.0f / 0.35f));

    float x1 = sg[(i1 >> 1) * 12 + 6 + (i1 & 1)];
    float y1 = sg[(i1 >> 1) * 12 + 8 + (i1 & 1)];
    float x2 = sg[(i2 >> 1) * 12 + 6 + (i2 & 1)];
    float y2 = sg[(i2 >> 1) * 12 + 8 + (i2 & 1)];
    float ddx   = x1 - x2;
    float ddy   = y1 - y2;
    float pdist = __builtin_amdgcn_sqrtf(fmaf(ddx, ddx, fmaf(ddy, ddy, EPSF)));
    float wmax  = fmaxf(0.8f * pdist, W_MINF + EPSF);
    float sij   = sigm(w_raw[i1 * S + i2] * 0.2f);   // /RAW_TEMP(5)
    float sji   = sigm(w_raw[i2 * S + i1] * 0.2f);
    float wpair = W_MINF + (wmax - W_MINF) * 0.5f * (sij + sji);

    float weff     = wpair * fmaf(0.15f, jfac, 1.0f);
    float beta_eff = BETAF * fmaf(0.05f, jfac, 1.0f);
    float wall     = sigm((weff - gap) / beta_eff);

    float gap_thr = 0.5f  * sigm(gap_thr_raw[0]);
    float big_thr = 0.6f  * sigm(big_thr_raw[0]);
    float alpha_g = 0.01f + 0.19f * sigm(alpha_raw[0]);
    float eta_g   = 0.01f + 0.19f * sigm(eta_raw[0]);

    float gate = sigm((gap_thr - gap) / alpha_g) * sigm((big_thr - d1) / eta_g);

    float t      = fmaxf(keff - 3.0f, 0.0f);
    float triple = 0.15f * t * __builtin_amdgcn_sqrtf(t);

    float h   = 0.5f + 1.5f * sigm(h_raw[0]);
    float occ = fminf(fmaxf(fmaf(wall, gate, triple), 0.0f), 1.0f);
    if (q < Q) out[q] = occ * h;
}

extern "C" void kernel_launch(void* const* d_in, const int* in_sizes, int n_in,
                              void* d_out, int out_size, void* d_ws, size_t ws_size,
                              hipStream_t stream)
{
    const float* uv          = (const float*)d_in[0];
    const float* seeds_raw   = (const float*)d_in[1];
    const float* w_raw       = (const float*)d_in[2];
    const float* h_raw       = (const float*)d_in[3];
    const float* theta       = (const float*)d_in[4];
    const float* a_raw       = (const float*)d_in[5];
    const float* gap_thr_raw = (const float*)d_in[6];
    const float* big_thr_raw = (const float*)d_in[7];
    const float* alpha_raw   = (const float*)d_in[8];
    const float* eta_raw     = (const float*)d_in[9];
    float* out = (float*)d_out;

    const int Q = in_sizes[0] / 2;
    const int S = in_sizes[4];

    dim3 block(512);                      // 8 waves: 8 seed-partitions
    dim3 grid((Q + 63) / 64);             // 64 queries per block
    voronoi_kernel<<<grid, block, 0, stream>>>(uv, seeds_raw, theta, a_raw,
                                               w_raw, h_raw,
                                               gap_thr_raw, big_thr_raw,
                                               alpha_raw, eta_raw,
                                               out, Q, S);
}

// Round 9
// 85.246 us; speedup vs baseline: 1.0439x; 1.0198x over previous
//
#include <hip/hip_runtime.h>
#include <math.h>

#define EPSF    1e-8f
#define W_MINF  0.005f
#define BETAF   0.02f
#define LOG2E   1.4426950408889634f

constexpr double KD    = 1.4426950408889634 / 0.02;   // log2(e)/beta
constexpr float  K2F   = (float)(KD * KD);            // folded into A,B,C
constexpr float  K2EPS = (float)(KD * KD * 1e-8);     // scaled eps
constexpr float  INVK  = (float)(1.0 / KD);

typedef float v2f __attribute__((ext_vector_type(2)));
typedef float v4f __attribute__((ext_vector_type(4)));

__device__ __forceinline__ float fast_exp(float x) {   // e^x
    return __builtin_amdgcn_exp2f(x * LOG2E);
}
__device__ __forceinline__ float sigm(float x) {       // 1/(1+e^-x)
    return 1.0f / (1.0f + fast_exp(-x));
}
__device__ __forceinline__ float ex2(float x) { return __builtin_amdgcn_exp2f(x); }

__device__ __forceinline__ unsigned min3u(unsigned a, unsigned b, unsigned c) {
    unsigned d;
    asm("v_min3_u32 %0, %1, %2, %3" : "=v"(d) : "v"(a), "v"(b), "v"(c));
    return d;
}
__device__ __forceinline__ unsigned med3u(unsigned a, unsigned b, unsigned c) {
    unsigned d;
    asm("v_med3_u32 %0, %1, %2, %3" : "=v"(d) : "v"(a), "v"(b), "v"(c));
    return d;
}

// Fused kernel: 64 queries/block (lanes), 8 waves = 8 seed partitions of 64.
// 4 seeds per iteration, two independent accumulator pairs (ILP).
// LDS group layout (4 seeds, 20 floats / 80 B): [A×4|B×4|C×4|X×4|Y×4]
//   -> 5x ds_read_b128 wave-uniform broadcast per iteration.
extern "C" __global__ __launch_bounds__(512, 8)
void voronoi_kernel(const float* __restrict__ uv,
                    const float* __restrict__ seeds,
                    const float* __restrict__ theta,
                    const float* __restrict__ a_raw,
                    const float* __restrict__ w_raw,
                    const float* __restrict__ h_raw,
                    const float* __restrict__ gap_thr_raw,
                    const float* __restrict__ big_thr_raw,
                    const float* __restrict__ alpha_raw,
                    const float* __restrict__ eta_raw,
                    float* __restrict__ out,
                    int Q, int S)
{
    __shared__ float sg[128 * 20];                    // 10 KB seed table
    __shared__ unsigned mv1[8][64], mv2[8][64];       //  4 KB
    __shared__ float    ms1[8][64], ms2[8][64];       //  4 KB

    const int tid = threadIdx.x;
    {   // in-block seed prep: thread tid preps seed tid (blockDim == S == 512)
        const int j = tid;
        float sx = seeds[2 * j + 0];
        float sy = seeds[2 * j + 1];
        float sn, cs;
        __sincosf(theta[j], &sn, &cs);
        float a   = 0.5f + 1.5f * sigm(a_raw[j]);
        float a2  = a * a;
        float ia2 = 1.0f / a2;
        float c2 = cs * cs, s2 = sn * sn;
        float* p = &sg[(j >> 2) * 20 + (j & 3)];
        p[0]  = K2F * (c2 * a2 + s2 * ia2);           // A
        p[4]  = K2F * (s2 * a2 + c2 * ia2);           // B
        p[8]  = K2F * (cs * sn * (a2 - ia2));         // C
        p[12] = sx;                                   // X
        p[16] = sy;                                   // Y
    }
    __syncthreads();

    const int part = __builtin_amdgcn_readfirstlane((int)(tid >> 6));
    const int lane = tid & 63;
    const int q    = blockIdx.x * 64 + lane;
    const int qc   = q < Q ? q : (Q - 1);

    const float2 u = *reinterpret_cast<const float2*>(&uv[2 * qc]);
    const v2f uxv  = { u.x, u.x };
    const v2f uyv  = { u.y, u.y };
    const v2f epsv = { K2EPS, K2EPS };

    unsigned v1u = 0x7F7FFFFFu, v2u = 0x7F7FFFFFu;  // packed (r-bits|index)
    v2f s1a = { 0.0f, 0.0f }, s2a = { 0.0f, 0.0f };
    v2f s1b = { 0.0f, 0.0f }, s2b = { 0.0f, 0.0f };

    const int gbase = part * 16;                     // 16 groups = 64 seeds
    #pragma unroll 4
    for (int g = 0; g < 16; ++g) {
        const float* pp = &sg[(gbase + g) * 20];     // wave-uniform broadcast
        const v4f Av = *reinterpret_cast<const v4f*>(pp + 0);
        const v4f Bv = *reinterpret_cast<const v4f*>(pp + 4);
        const v4f Cv = *reinterpret_cast<const v4f*>(pp + 8);
        const v4f Xv = *reinterpret_cast<const v4f*>(pp + 12);
        const v4f Yv = *reinterpret_cast<const v4f*>(pp + 16);

        // pair 0: seeds 4g, 4g+1
        {
            const v2f A = { Av.x, Av.y }, B = { Bv.x, Bv.y };
            const v2f C = { Cv.x, Cv.y }, X = { Xv.x, Xv.y }, Y = { Yv.x, Yv.y };
            v2f dx = uxv - X;
            v2f dy = uyv - Y;
            v2f p  = __builtin_elementwise_fma(A, dx, C * dy);
            v2f qv = __builtin_elementwise_fma(C, dx, B * dy);
            v2f r  = __builtin_elementwise_fma(
                         dx, p, __builtin_elementwise_fma(dy, qv, epsv));
            float e0 = ex2(-__builtin_amdgcn_sqrtf(r.x));
            float e1 = ex2(-__builtin_amdgcn_sqrtf(r.y));
            v2f e = { e0, e1 };
            s1a = s1a + e;
            s2a = __builtin_elementwise_fma(e, e, s2a);
            const int j0 = (gbase + g) * 4;
            unsigned pv0 = (__float_as_uint(r.x) & 0xFFFFFE00u) | (unsigned)j0;
            unsigned pv1 = (__float_as_uint(r.y) & 0xFFFFFE00u) | (unsigned)(j0 + 1);
            unsigned m2  = med3u(v1u, pv0, pv1);
            v1u = min3u(v1u, pv0, pv1);
            v2u = v2u < m2 ? v2u : m2;
        }
        // pair 1: seeds 4g+2, 4g+3
        {
            const v2f A = { Av.z, Av.w }, B = { Bv.z, Bv.w };
            const v2f C = { Cv.z, Cv.w }, X = { Xv.z, Xv.w }, Y = { Yv.z, Yv.w };
            v2f dx = uxv - X;
            v2f dy = uyv - Y;
            v2f p  = __builtin_elementwise_fma(A, dx, C * dy);
            v2f qv = __builtin_elementwise_fma(C, dx, B * dy);
            v2f r  = __builtin_elementwise_fma(
                         dx, p, __builtin_elementwise_fma(dy, qv, epsv));
            float e0 = ex2(-__builtin_amdgcn_sqrtf(r.x));
            float e1 = ex2(-__builtin_amdgcn_sqrtf(r.y));
            v2f e = { e0, e1 };
            s1b = s1b + e;
            s2b = __builtin_elementwise_fma(e, e, s2b);
            const int j0 = (gbase + g) * 4 + 2;
            unsigned pv0 = (__float_as_uint(r.x) & 0xFFFFFE00u) | (unsigned)j0;
            unsigned pv1 = (__float_as_uint(r.y) & 0xFFFFFE00u) | (unsigned)(j0 + 1);
            unsigned m2  = med3u(v1u, pv0, pv1);
            v1u = min3u(v1u, pv0, pv1);
            v2u = v2u < m2 ? v2u : m2;
        }
    }

    v2f s1v = s1a + s1b;
    v2f s2v = s2a + s2b;
    float s1 = s1v.x + s1v.y;
    float s2 = s2v.x + s2v.y;

    // ---- merge 8 per-wave partials through LDS ---------------------------
    mv1[part][lane] = v1u;  mv2[part][lane] = v2u;
    ms1[part][lane] = s1;   ms2[part][lane] = s2;
    __syncthreads();
    if (part != 0) return;

    unsigned V1 = mv1[0][lane], V2 = mv2[0][lane];
    float    S1 = ms1[0][lane], S2 = ms2[0][lane];
    #pragma unroll
    for (int p2 = 1; p2 < 8; ++p2) {
        unsigned w1 = mv1[p2][lane], w2 = mv2[p2][lane];
        S1 += ms1[p2][lane];
        S2 += ms2[p2][lane];
        unsigned n1 = V1 < w1 ? V1 : w1;
        unsigned hi = V1 > w1 ? V1 : w1;
        unsigned l2 = V2 < w2 ? V2 : w2;
        V2 = hi < l2 ? hi : l2;
        V1 = n1;
    }

    const int i1 = (int)(V1 & 511u);
    const int i2 = (int)(V2 & 511u);
    float d1K = __builtin_amdgcn_sqrtf(__uint_as_float(V1));   // K*d1
    float d2K = __builtin_amdgcn_sqrtf(__uint_as_float(V2));
    float d1  = d1K * INVK;
    float gap = (d2K - d1K) * INVK;

    float sp2  = (S2 / S1) / S1;                 // sum p^2 (underflow-safe)
    float keff = 1.0f / (sp2 + EPSF);
    float jfac = sigm((keff - 3.0f) * (1.0f / 0.35f));

    float x1 = sg[(i1 >> 2) * 20 + 12 + (i1 & 3)];
    float y1 = sg[(i1 >> 2) * 20 + 16 + (i1 & 3)];
    float x2 = sg[(i2 >> 2) * 20 + 12 + (i2 & 3)];
    float y2 = sg[(i2 >> 2) * 20 + 16 + (i2 & 3)];
    float ddx   = x1 - x2;
    float ddy   = y1 - y2;
    float pdist = __builtin_amdgcn_sqrtf(fmaf(ddx, ddx, fmaf(ddy, ddy, EPSF)));
    float wmax  = fmaxf(0.8f * pdist, W_MINF + EPSF);
    float sij   = sigm(w_raw[i1 * S + i2] * 0.2f);   // /RAW_TEMP(5)
    float sji   = sigm(w_raw[i2 * S + i1] * 0.2f);
    float wpair = W_MINF + (wmax - W_MINF) * 0.5f * (sij + sji);

    float weff     = wpair * fmaf(0.15f, jfac, 1.0f);
    float beta_eff = BETAF * fmaf(0.05f, jfac, 1.0f);
    float wall     = sigm((weff - gap) / beta_eff);

    float gap_thr = 0.5f  * sigm(gap_thr_raw[0]);
    float big_thr = 0.6f  * sigm(big_thr_raw[0]);
    float alpha_g = 0.01f + 0.19f * sigm(alpha_raw[0]);
    float eta_g   = 0.01f + 0.19f * sigm(eta_raw[0]);

    float gate = sigm((gap_thr - gap) / alpha_g) * sigm((big_thr - d1) / eta_g);

    float t      = fmaxf(keff - 3.0f, 0.0f);
    float triple = 0.15f * t * __builtin_amdgcn_sqrtf(t);

    float h   = 0.5f + 1.5f * sigm(h_raw[0]);
    float occ = fminf(fmaxf(fmaf(wall, gate, triple), 0.0f), 1.0f);
    if (q < Q) out[q] = occ * h;
}

extern "C" void kernel_launch(void* const* d_in, const int* in_sizes, int n_in,
                              void* d_out, int out_size, void* d_ws, size_t ws_size,
                              hipStream_t stream)
{
    const float* uv          = (const float*)d_in[0];
    const float* seeds_raw   = (const float*)d_in[1];
    const float* w_raw       = (const float*)d_in[2];
    const float* h_raw       = (const float*)d_in[3];
    const float* theta       = (const float*)d_in[4];
    const float* a_raw       = (const float*)d_in[5];
    const float* gap_thr_raw = (const float*)d_in[6];
    const float* big_thr_raw = (const float*)d_in[7];
    const float* alpha_raw   = (const float*)d_in[8];
    const float* eta_raw     = (const float*)d_in[9];
    float* out = (float*)d_out;

    const int Q = in_sizes[0] / 2;
    const int S = in_sizes[4];

    dim3 block(512);                      // 8 waves: 8 seed-partitions
    dim3 grid((Q + 63) / 64);             // 64 queries per block
    voronoi_kernel<<<grid, block, 0, stream>>>(uv, seeds_raw, theta, a_raw,
                                               w_raw, h_raw,
                                               gap_thr_raw, big_thr_raw,
                                               alpha_raw, eta_raw,
                                               out, Q, S);
}